// Round 7
// baseline (720.650 us; speedup 1.0000x reference)
//
#include <hip/hip_runtime.h>
#include <hip/hip_bf16.h>

#define NROW 8192
#define DIM 256

typedef short bf16x8 __attribute__((ext_vector_type(8)));
typedef float f32x4 __attribute__((ext_vector_type(4)));

__device__ __forceinline__ short f2bf(float x) {
    return __builtin_bit_cast(short, __float2bfloat16(x));
}

__device__ __forceinline__ void gload_lds16(const void* g, void* l) {
    __builtin_amdgcn_global_load_lds(
        (const __attribute__((address_space(1))) unsigned int*)g,
        (__attribute__((address_space(3))) unsigned int*)l, 16, 0, 0);
}

// t = adj>0 ? exp(lrelu(fi+fj)) : 0
__device__ __forceinline__ float lrexpi(int m, float fj, float fi) {
    float x = fi + fj;
    return m > 0 ? __expf(fmaxf(x, 0.2f * x)) : 0.f;
}
__device__ __forceinline__ float sum4i(int4 m, float4 fv, float fi) {
    return lrexpi(m.x, fv.x, fi) + lrexpi(m.y, fv.y, fi) +
           lrexpi(m.z, fv.z, fi) + lrexpi(m.w, fv.w, fi);
}
// pass2 variant: adj bits arrive in float regs from asm loads; compare as int
__device__ __forceinline__ float lrexpb(float bits, float fj, float fi) {
    int m = __builtin_bit_cast(int, bits);
    float x = fi + fj;
    return m > 0 ? __expf(fmaxf(x, 0.2f * x)) : 0.f;
}
__device__ __forceinline__ float4 lrexp4(f32x4 a, float4 fv, float fi) {
    float4 r;
    r.x = lrexpb(a[0], fv.x, fi);
    r.y = lrexpb(a[1], fv.y, fi);
    r.z = lrexpb(a[2], fv.z, fi);
    r.w = lrexpb(a[3], fv.w, fi);
    return r;
}

// ---------------------------------------------------------------------------
// k1: Wh = h @ W (fp32 accum). Epilogue: f[j] += Wh[j][:] . a  (atomic partial
// per 64-col block) and whbT in K-TILED layout for k45's global_load_lds:
//   whbT[((k>>6)*256 + n)*64 + (k&63)] = bf16(Wh[k][n])
// grid (128, 4), block 256
// ---------------------------------------------------------------------------
__global__ __launch_bounds__(256) void k1_whgemm(
    const float* __restrict__ h, const float* __restrict__ W,
    const float* __restrict__ a, short* __restrict__ whbT,
    float* __restrict__ f)
{
    __shared__ float hs[64][65];
    __shared__ float wsm[64][65];
    const int tid = threadIdx.x;
    const int tx = tid & 15, ty = tid >> 4;
    const int i0 = blockIdx.x * 64;
    const int n0 = blockIdx.y * 64;

    float acc[4][4];
#pragma unroll
    for (int u = 0; u < 4; ++u)
#pragma unroll
        for (int v = 0; v < 4; ++v) acc[u][v] = 0.f;

    for (int kb = 0; kb < DIM; kb += 64) {
#pragma unroll
        for (int rr = 0; rr < 4; ++rr) {
            int row = rr * 16 + ty;
            *(float4*)&hs[row][tx * 4] =
                *(const float4*)&h[(size_t)(i0 + row) * DIM + kb + tx * 4];
            *(float4*)&wsm[row][tx * 4] =
                *(const float4*)&W[(size_t)(kb + row) * DIM + n0 + tx * 4];
        }
        __syncthreads();
#pragma unroll 8
        for (int kk = 0; kk < 64; ++kk) {
            float av[4], bv[4];
#pragma unroll
            for (int u = 0; u < 4; ++u) av[u] = hs[ty * 4 + u][kk];
#pragma unroll
            for (int v = 0; v < 4; ++v) bv[v] = wsm[kk][tx * 4 + v];
#pragma unroll
            for (int u = 0; u < 4; ++u)
#pragma unroll
                for (int v = 0; v < 4; ++v) acc[u][v] += av[u] * bv[v];
        }
        __syncthreads();
    }

#pragma unroll
    for (int u = 0; u < 4; ++u)
#pragma unroll
        for (int v = 0; v < 4; ++v) hs[ty * 4 + u][tx * 4 + v] = acc[u][v];
    __syncthreads();

    {
        int r = tid >> 2, q = tid & 3;
        float s = 0.f;
#pragma unroll
        for (int c = 0; c < 16; ++c) s += hs[r][q * 16 + c] * a[n0 + q * 16 + c];
        s += __shfl_xor(s, 1);
        s += __shfl_xor(s, 2);
        if (q == 0) atomicAdd(&f[i0 + r], s);
    }

    {
        int n = tid >> 2, q = tid & 3;
        union { short s[16]; int4 i4[2]; } pk;
#pragma unroll
        for (int b = 0; b < 4; ++b)
#pragma unroll
            for (int c = 0; c < 4; ++c)
                pk.s[b * 4 + c] = f2bf(hs[q * 16 + b * 4 + c][n]);
        size_t base = ((size_t)(i0 >> 6) * 256 + n0 + n) * 64 + q * 16;
        *(int4*)&whbT[base] = pk.i4[0];
        *(int4*)&whbT[base + 8] = pk.i4[1];
    }
}

// ---------------------------------------------------------------------------
// k45: fused alpha + out0. Block = 128 rows x 64 cols, full K, grid 256
// (XCD-pinned decode, proven in k4g), 512 threads = 8 waves (wave=16 rows).
// f (32 KB) cached in LDS.
// pass1 (PLAIN C++, no asm): rowsum of t via 4-set static ping-pong int4
// loads (lookahead ~3 tiles), compiler-scheduled. 2 shfl_xor -> inv.
// pass2: the k4g depth-2 counted-vmcnt MFMA pipeline VERBATIM; A-operand =
// bf16(t*inv) recomputed from adj (asm-loaded bits) + f_sh; owner col-split
// (kt&3==cs) stores scaled f32 alpha; elu fused into epilogue.
// ---------------------------------------------------------------------------
__global__ __launch_bounds__(512) void k45_fused(
    const int* __restrict__ adj, const float* __restrict__ f,
    const short* __restrict__ whbT, float* __restrict__ alpha,
    float* __restrict__ out0)
{
    __shared__ float f_sh[NROW];                  // 32 KB
    __shared__ __align__(16) short Bs[4][4096];   // 4 x 8 KB = 32 KB

    const int tid = threadIdx.x;
    const int wave = tid >> 6;
    const int lane = tid & 63;
    const int lo = lane & 15;
    const int quad = lane >> 4;
    const int q8 = quad * 8;

    // XCD-pinned decode (k4g): col-splits of a row-block share an XCD L2.
    const int bid = blockIdx.x;
    const int xcd = bid & 7;
    const int slot = bid >> 3;            // 0..31
    const int rb = xcd * 8 + (slot & 7);  // 0..63
    const int cs = slot >> 3;             // 0..3
    const int i0 = rb * 128;
    const int n0 = cs * 64;

    // f -> LDS (512 threads x 16 floats)
#pragma unroll
    for (int u = 0; u < 4; ++u)
        *(float4*)&f_sh[u * 2048 + tid * 4] =
            *(const float4*)&f[u * 2048 + tid * 4];
    __syncthreads();

    const int myrow = i0 + wave * 16 + lo;
    const float fi = f_sh[myrow];
    const int* adji = adj + (size_t)myrow * NROW + q8;

    // ------------------------- pass 1: row sums (plain C++) ----------------
    float rsum = 0.f;
    {
        int4 A0, A1, A2, A3, B0, B1, B2, B3;
        int4 C0, C1, C2, C3, D0, D1, D2, D3;

#define LOADI(P, kt)                                                          \
        {                                                                     \
            const int* p = adji + (size_t)(kt) * 64;                          \
            P##0 = *(const int4*)p;                                           \
            P##1 = *(const int4*)(p + 4);                                     \
            P##2 = *(const int4*)(p + 32);                                    \
            P##3 = *(const int4*)(p + 36);                                    \
        }

#define SUMI(P, kt)                                                           \
        {                                                                     \
            float4 F0 = *(const float4*)&f_sh[(kt) * 64 + q8];                \
            float4 F1 = *(const float4*)&f_sh[(kt) * 64 + q8 + 4];            \
            float4 F2 = *(const float4*)&f_sh[(kt) * 64 + 32 + q8];           \
            float4 F3 = *(const float4*)&f_sh[(kt) * 64 + 36 + q8];           \
            rsum += sum4i(P##0, F0, fi) + sum4i(P##1, F1, fi) +               \
                    sum4i(P##2, F2, fi) + sum4i(P##3, F3, fi);                \
        }

        LOADI(A, 0) LOADI(B, 1) LOADI(C, 2) LOADI(D, 3)
#pragma unroll 1
        for (int kt = 0; kt < 124; kt += 4) {
            SUMI(A, kt)     LOADI(A, kt + 4)
            SUMI(B, kt + 1) LOADI(B, kt + 5)
            SUMI(C, kt + 2) LOADI(C, kt + 6)
            SUMI(D, kt + 3) LOADI(D, kt + 7)
        }
        SUMI(A, 124) SUMI(B, 125) SUMI(C, 126) SUMI(D, 127)
#undef LOADI
#undef SUMI
    }

    rsum += __shfl_xor(rsum, 16);
    rsum += __shfl_xor(rsum, 32);
    const float inv = 1.f / rsum;

    // ------------------------- pass 2: MFMA + alpha (k4g skeleton) ---------
    // B staging (k4g, verified): linear LDS dest, XOR-swizzled source chunk.
    const int n_local = tid >> 3;
    const int schunk = ((tid & 7) ^ (n_local & 7)) * 8;
    const int bx0 = (quad ^ (lo & 7)) * 8;
    const int bx1 = ((4 + quad) ^ (lo & 7)) * 8;
    int off0[4], off1[4];
#pragma unroll
    for (int nt = 0; nt < 4; ++nt) {
        int rbase = (nt * 16 + lo) * 64;
        off0[nt] = rbase + bx0;
        off1[nt] = rbase + bx1;
    }

    const float* adjp = (const float*)adji;   // same row, float-bits view

    f32x4 pA[4], pB[4], pC[4], pD[4];   // adj prefetch sets, static idx only
    f32x4 acc[4] = {};

#define STAGE(buf, kt)                                                        \
    {                                                                         \
        const short* gsrc = whbT + (size_t)(kt) * 16384 +                     \
                            (n0 + n_local) * 64 + schunk;                     \
        gload_lds16(gsrc, &Bs[buf][tid * 8]);                                 \
    }

#define ALOAD(set, kt)                                                        \
    {                                                                         \
        const float* ap = adjp + (size_t)(kt) * 64;                           \
        asm volatile("global_load_dwordx4 %0, %4, off\n\t"                    \
                     "global_load_dwordx4 %1, %4, off offset:16\n\t"          \
                     "global_load_dwordx4 %2, %4, off offset:128\n\t"         \
                     "global_load_dwordx4 %3, %4, off offset:144"             \
                     : "=&v"(pA[set]), "=&v"(pB[set]),                        \
                       "=&v"(pC[set]), "=&v"(pD[set])                         \
                     : "v"(ap));                                              \
    }

#define CONSUME(c, kt)                                                        \
    {                                                                         \
        float4 F0 = *(const float4*)&f_sh[(kt) * 64 + q8];                    \
        float4 F1 = *(const float4*)&f_sh[(kt) * 64 + q8 + 4];                \
        float4 F2 = *(const float4*)&f_sh[(kt) * 64 + 32 + q8];               \
        float4 F3 = *(const float4*)&f_sh[(kt) * 64 + 36 + q8];               \
        float4 t0 = lrexp4(pA[c], F0, fi);                                    \
        float4 t1 = lrexp4(pB[c], F1, fi);                                    \
        float4 t2 = lrexp4(pC[c], F2, fi);                                    \
        float4 t3 = lrexp4(pD[c], F3, fi);                                    \
        float4 s0 = make_float4(t0.x * inv, t0.y * inv, t0.z * inv,           \
                                t0.w * inv);                                  \
        float4 s1 = make_float4(t1.x * inv, t1.y * inv, t1.z * inv,           \
                                t1.w * inv);                                  \
        float4 s2 = make_float4(t2.x * inv, t2.y * inv, t2.z * inv,           \
                                t2.w * inv);                                  \
        float4 s3 = make_float4(t3.x * inv, t3.y * inv, t3.z * inv,           \
                                t3.w * inv);                                  \
        if (((kt) & 3) == cs) {                                               \
            float* arow = alpha + (size_t)myrow * NROW + (kt) * 64 + q8;      \
            *(float4*)arow = s0;                                              \
            *(float4*)(arow + 4) = s1;                                        \
            *(float4*)(arow + 32) = s2;                                       \
            *(float4*)(arow + 36) = s3;                                       \
        }                                                                     \
        bf16x8 af0, af1;                                                      \
        af0[0] = f2bf(s0.x); af0[1] = f2bf(s0.y);                             \
        af0[2] = f2bf(s0.z); af0[3] = f2bf(s0.w);                             \
        af0[4] = f2bf(s1.x); af0[5] = f2bf(s1.y);                             \
        af0[6] = f2bf(s1.z); af0[7] = f2bf(s1.w);                             \
        af1[0] = f2bf(s2.x); af1[1] = f2bf(s2.y);                             \
        af1[2] = f2bf(s2.z); af1[3] = f2bf(s2.w);                             \
        af1[4] = f2bf(s3.x); af1[5] = f2bf(s3.y);                             \
        af1[6] = f2bf(s3.z); af1[7] = f2bf(s3.w);                             \
        _Pragma("unroll")                                                     \
        for (int nt = 0; nt < 4; ++nt) {                                      \
            bf16x8 b0 = *(const bf16x8*)&Bs[c][off0[nt]];                     \
            acc[nt] = __builtin_amdgcn_mfma_f32_16x16x32_bf16(af0, b0,        \
                                                          acc[nt], 0, 0, 0);  \
            bf16x8 b1 = *(const bf16x8*)&Bs[c][off1[nt]];                     \
            acc[nt] = __builtin_amdgcn_mfma_f32_16x16x32_bf16(af1, b1,        \
                                                          acc[nt], 0, 0, 0);  \
        }                                                                     \
    }

#define KSTEP(kt, c, DO, N)                                                   \
    {                                                                         \
        if (DO) { STAGE(((c) + 2) & 3, (kt) + 2); ALOAD(((c) + 2) & 3,        \
                                                        (kt) + 2); }          \
        asm volatile("s_waitcnt vmcnt(" #N ")" ::: "memory");                 \
        __builtin_amdgcn_s_barrier();                                         \
        __builtin_amdgcn_sched_barrier(0);                                    \
        CONSUME(c, kt)                                                        \
    }

    STAGE(0, 0); ALOAD(0, 0);
    STAGE(1, 1); ALOAD(1, 1);

#pragma unroll 1
    for (int base = 0; base < 124; base += 4) {
        KSTEP(base + 0, 0, true, 10)
        KSTEP(base + 1, 1, true, 10)
        KSTEP(base + 2, 2, true, 10)
        KSTEP(base + 3, 3, true, 10)
    }
    KSTEP(124, 0, true, 10)    // stages tile 126
    KSTEP(125, 1, true, 10)    // stages tile 127
    KSTEP(126, 2, false, 5)
    KSTEP(127, 3, false, 0)

#undef STAGE
#undef ALOAD
#undef CONSUME
#undef KSTEP

    // C/D layout: col = lane&15, row = quad*4 + reg. acc already inv-scaled.
    const int ccb = n0 + lo;
#pragma unroll
    for (int nt = 0; nt < 4; ++nt) {
#pragma unroll
        for (int c = 0; c < 4; ++c) {
            const int rr = i0 + wave * 16 + quad * 4 + c;
            float v = acc[nt][c];
            v = v > 0.f ? v : __expf(v) - 1.f;
            out0[(size_t)rr * DIM + ccb + nt * 16] = v;
        }
    }
}

extern "C" void kernel_launch(void* const* d_in, const int* in_sizes, int n_in,
                              void* d_out, int out_size, void* d_ws, size_t ws_size,
                              hipStream_t stream) {
    const float* h = (const float*)d_in[0];
    const int* adj = (const int*)d_in[1];
    const float* W = (const float*)d_in[2];
    const float* a = (const float*)d_in[3];
    float* out0 = (float*)d_out;                        // elu(h_prime) [8192,256]
    float* alpha = out0 + (size_t)NROW * DIM;           // alpha [8192,8192]

    char* ws = (char*)d_ws;
    float* f = (float*)ws;                              // 32 KB
    short* whbT = (short*)(ws + 32768);                 // 4 MB bf16, K-tiled

    hipMemsetAsync(f, 0, NROW * sizeof(float), stream);
    k1_whgemm<<<dim3(NROW / 64, DIM / 64), 256, 0, stream>>>(h, W, a, whbT, f);
    k45_fused<<<dim3(256), 512, 0, stream>>>(adj, f, whbT, alpha, out0);
}